// Round 1
// baseline (1445.379 us; speedup 1.0000x reference)
//
#include <hip/hip_runtime.h>
#include <math.h>

#define BG 8
#define NN 20000
#define EE 320000
#define CC 128
#define DD 64
#define NHOPS 4
#define HID 512
#define OUTD 256

typedef __attribute__((ext_vector_type(8))) short short8;
typedef __attribute__((ext_vector_type(4))) float f32x4;

__device__ __forceinline__ unsigned short f2bf(float f) {
    unsigned u = __float_as_uint(f);
    u += 0x7fffu + ((u >> 16) & 1u);  // RNE
    return (unsigned short)(u >> 16);
}

// LDS lane swizzle: spread epilogue-repack writes across banks.
// bit0 ^= bit4, bit1 ^= bit3. Involution => bijection.
__device__ __forceinline__ int swz(int la) {
    return la ^ ((la >> 4) & 1) ^ (((la >> 3) & 1) << 1);
}

// ---------------- small prep kernels ----------------

__global__ __launch_bounds__(256) void zero_kernel(int* __restrict__ p, int n) {
    int i = blockIdx.x * 256 + threadIdx.x;
    if (i < n) p[i] = 0;
}

__global__ __launch_bounds__(256) void argmax_kernel(const float* __restrict__ P, int* __restrict__ idx) {
    int n = blockIdx.x * 256 + threadIdx.x;
    if (n >= NN) return;
    float best = P[n];
    int bi = 0;
    #pragma unroll 4
    for (int c = 1; c < CC; ++c) {
        float v = P[c * NN + n];
        if (v > best) { best = v; bi = c; }
    }
    idx[n] = bi;
}

__global__ __launch_bounds__(256) void hist_kernel(const int* __restrict__ ei, int* __restrict__ counts) {
    int i = blockIdx.x * 256 + threadIdx.x;
    int b = i / EE, e = i - b * EE;
    int row = ei[(long)b * 2 * EE + e];
    atomicAdd(&counts[b * NN + row], 1);
}

__global__ __launch_bounds__(256) void scan_kernel(const int* __restrict__ counts, int* __restrict__ row_ptr,
                                                   int* __restrict__ cursor) {
    const int b = blockIdx.x, t = threadIdx.x;
    const int CH = (NN + 255) / 256;
    const int* cnt = counts + b * NN;
    int s0 = t * CH, s1 = min(s0 + CH, NN);
    int sum = 0;
    for (int i = s0; i < s1; ++i) sum += cnt[i];
    __shared__ int ss[256];
    ss[t] = sum;
    __syncthreads();
    for (int off = 1; off < 256; off <<= 1) {
        int v = (t >= off) ? ss[t - off] : 0;
        __syncthreads();
        ss[t] += v;
        __syncthreads();
    }
    int run = ss[t] - sum;
    int* rp = row_ptr + b * (NN + 1);
    int* cur = cursor + b * NN;
    for (int i = s0; i < s1; ++i) {
        rp[i] = run;
        cur[i] = run;
        run += cnt[i];
    }
    if (t == 255) rp[NN] = ss[255];
}

__global__ __launch_bounds__(256) void scatter_kernel(const int* __restrict__ ei, int* __restrict__ cursor,
                                                      int* __restrict__ col_sorted) {
    int i = blockIdx.x * 256 + threadIdx.x;
    int b = i / EE, e = i - b * EE;
    const int* eb = ei + (long)b * 2 * EE;
    int row = eb[e], col = eb[EE + e];
    int pos = atomicAdd(&cursor[b * NN + row], 1);
    col_sorted[(long)b * EE + pos] = col;
}

// ---------------- SPMM ----------------
// One wave per node. lane = (e4 = lane>>4 edge slot, d4 = lane&15 float4 slot).
// 4 independent gather chains per wave; float4 (16B) row loads; shfl reduce at end.
// XCD pinning: blockIdx.x & 7 = graph b => graph b's gather working set (5.12 MB)
// stays (mostly) in XCD b's 4 MB L2 instead of bouncing to L3.

// Hop 1: H1[n] = sum_cols emb[idx[col]] — gather the 32 KB table (L1-resident),
// not the 5 MB materialized init_emb.
__global__ __launch_bounds__(256) void spmm_first_kernel(const int* __restrict__ idx, const float* __restrict__ emb,
                                                         const int* __restrict__ row_ptr,
                                                         const int* __restrict__ col_sorted,
                                                         float* __restrict__ Hout) {
    int wave = threadIdx.x >> 6, lane = threadIdx.x & 63;
    int b = blockIdx.x & 7;
    int n = (blockIdx.x >> 3) * 4 + wave;
    const int* rp = row_ptr + b * (NN + 1);
    int s = rp[n], e = rp[n + 1];
    const int* cs = col_sorted + (long)b * EE;
    int e4 = lane >> 4, d4 = lane & 15;
    f32x4 sum = (f32x4)(0.f);
    for (int j = s + e4; j < e; j += 4) {
        int cell = idx[cs[j]];
        sum += *(const f32x4*)&emb[(size_t)cell * DD + d4 * 4];
    }
    #pragma unroll
    for (int i = 0; i < 4; ++i) {
        sum[i] += __shfl_xor(sum[i], 16, 64);
        sum[i] += __shfl_xor(sum[i], 32, 64);
    }
    if (lane < 16) *(f32x4*)&Hout[((long)b * NN + n) * DD + d4 * 4] = sum;
}

__global__ __launch_bounds__(256) void spmm_kernel(const float* __restrict__ Hin,
                                                   const int* __restrict__ row_ptr,
                                                   const int* __restrict__ col_sorted, float* __restrict__ Hout) {
    int wave = threadIdx.x >> 6, lane = threadIdx.x & 63;
    int b = blockIdx.x & 7;
    int n = (blockIdx.x >> 3) * 4 + wave;
    const int* rp = row_ptr + b * (NN + 1);
    int s = rp[n], e = rp[n + 1];
    const float* hb = Hin + (long)b * (NN * DD);
    const int* cs = col_sorted + (long)b * EE;
    int e4 = lane >> 4, d4 = lane & 15;
    f32x4 sum = (f32x4)(0.f);
    for (int j = s + e4; j < e; j += 4) {
        int col = cs[j];
        sum += *(const f32x4*)&hb[(size_t)col * DD + d4 * 4];
    }
    #pragma unroll
    for (int i = 0; i < 4; ++i) {
        sum[i] += __shfl_xor(sum[i], 16, 64);
        sum[i] += __shfl_xor(sum[i], 32, 64);
    }
    if (lane < 16) *(f32x4*)&Hout[((long)b * NN + n) * DD + d4 * 4] = sum;
}

// ---------------- weight packing: bf16 B-fragment layout ----------------
// Omega is staged HOP-MAJOR: k' = h*64 + d. Compensate by permuting W1 rows here:
// fragment k' maps to original W1 row k = d*4 + h.
__global__ __launch_bounds__(256) void pack_w1_kernel(const float* __restrict__ W1, short* __restrict__ w1p) {
    int i = blockIdx.x * 256 + threadIdx.x;  // < 131072
    int j = i & 7, la = (i >> 3) & 63, kb = (i >> 9) & 7, ct = i >> 12;
    int kp = kb * 32 + ((la >> 4) & 3) * 8 + j;  // k' in [0,256), hop-major
    int h = kp >> 6, d = kp & 63;
    int k = d * 4 + h;  // reference W1 row (stack(...,-1).reshape => k = d*HOPS+h)
    int col = ct * 16 + (la & 15);
    w1p[i] = (short)f2bf(W1[k * HID + col]);
}

// W2 packed: i = ((ct*16+kb)*64+la)*8+j (unchanged ordering)
__global__ __launch_bounds__(256) void pack_w2_kernel(const float* __restrict__ W2, short* __restrict__ w2p) {
    int i = blockIdx.x * 256 + threadIdx.x;  // < 131072
    int j = i & 7, la = (i >> 3) & 63, kb = (i >> 9) & 15, ct = i >> 13;
    int k = kb * 32 + ((la >> 4) & 3) * 8 + j;
    int col = ct * 16 + (la & 15);
    w2p[i] = (short)f2bf(W2[k * OUTD + col]);
}

// ---------------- fused MFMA MLP ----------------
// 64 rows/block, 512 threads (8 waves): wave w owns GEMM1 cols [w*64,w*64+64),
// GEMM2 cols [w*32,w*32+32). 64 KB frag buffer => 2 blocks/CU = 16 waves/CU.
__global__ __launch_bounds__(512, 4) void mlp_mfma_kernel(const float* __restrict__ H,  // [hop][b][n][d]
                                                          const short* __restrict__ w1p,
                                                          const float* __restrict__ b1,
                                                          const float* __restrict__ gamma,
                                                          const float* __restrict__ beta,
                                                          const short* __restrict__ w2p,
                                                          const float* __restrict__ b2, float* __restrict__ out) {
    __shared__ short buf[32768];   // 64 KB: omega frags (32 KB) then xact frags (64 KB)
    __shared__ float s1a[64 * 8];  // LN partials, separate so no extra barrier
    __shared__ float s2a[64 * 8];
    const int t = threadIdx.x;
    const int w = t >> 6, l = t & 63;
    const int q = l >> 4, cl = l & 15;
    const int lF = swz(l);
    const long g0 = (long)blockIdx.x * 64;

    // ---- Phase 1: stage omega[64][256] (k' = h*64+d) as bf16 A-fragments ----
    // Per chunk: 8 consecutive d of one hop plane = 32B contiguous global,
    // one 16B fragment slot in LDS.
    {
        const int rsub = l >> 3, oct = l & 7;
        #pragma unroll
        for (int i = 0; i < 4; ++i) {
            int task = i * 8 + w;  // 32 tasks = 4 hops x 8 row-groups
            int h = task >> 3, rg = task & 7;
            int r = rg * 8 + rsub;
            const float* src = H + ((long)h * (BG * NN) + g0 + r) * DD + oct * 8;
            f32x4 v0 = *(const f32x4*)src;
            f32x4 v1 = *(const f32x4*)(src + 4);
            short8 frag;
            frag[0] = (short)f2bf(v0[0]);
            frag[1] = (short)f2bf(v0[1]);
            frag[2] = (short)f2bf(v0[2]);
            frag[3] = (short)f2bf(v0[3]);
            frag[4] = (short)f2bf(v1[0]);
            frag[5] = (short)f2bf(v1[1]);
            frag[6] = (short)f2bf(v1[2]);
            frag[7] = (short)f2bf(v1[3]);
            int kb = (h << 1) | (oct >> 2);  // k0 = h*64+oct*8; kb = k0>>5
            int quad = oct & 3;
            int rt = r >> 4;
            int la = (r & 15) | (quad << 4);
            *(short8*)&buf[((rt * 8 + kb) * 64 + swz(la)) * 8] = frag;
        }
    }
    __syncthreads();

    // ---- Phase 2: GEMM1: acc[rt][c] = omega(64x256) @ W1(256x512) wave-slice ----
    f32x4 acc[4][4];
    #pragma unroll
    for (int rt = 0; rt < 4; ++rt)
        #pragma unroll
        for (int c = 0; c < 4; ++c) acc[rt][c] = (f32x4)(0.f);
    #pragma unroll 2
    for (int kb = 0; kb < 8; ++kb) {
        short8 a[4];
        #pragma unroll
        for (int rt = 0; rt < 4; ++rt) a[rt] = *(const short8*)&buf[((rt * 8 + kb) * 64 + lF) * 8];
        #pragma unroll
        for (int c = 0; c < 4; ++c) {
            const short8 bfr = *(const short8*)(w1p + (((size_t)(w * 4 + c) * 8 + kb) * 64 + l) * 8);
            #pragma unroll
            for (int rt = 0; rt < 4; ++rt)
                acc[rt][c] = __builtin_amdgcn_mfma_f32_16x16x32_bf16(a[rt], bfr, acc[rt][c], 0, 0, 0);
        }
    }

    // ---- Phase 3: bias + row partial sums -> LDS ----
    float b1v[4], gv[4], bv[4];
    #pragma unroll
    for (int c = 0; c < 4; ++c) {
        int col = (w * 4 + c) * 16 + cl;
        b1v[c] = b1[col];
        gv[c] = gamma[col];
        bv[c] = beta[col];
    }
    float s1[4][4], s2[4][4];
    #pragma unroll
    for (int rt = 0; rt < 4; ++rt)
        #pragma unroll
        for (int i = 0; i < 4; ++i) {
            float a = 0.f, bb = 0.f;
            #pragma unroll
            for (int c = 0; c < 4; ++c) {
                float x = acc[rt][c][i] + b1v[c];
                acc[rt][c][i] = x;
                a += x;
                bb += x * x;
            }
            s1[rt][i] = a;
            s2[rt][i] = bb;
        }
    #pragma unroll
    for (int m = 1; m < 16; m <<= 1)
        #pragma unroll
        for (int rt = 0; rt < 4; ++rt)
            #pragma unroll
            for (int i = 0; i < 4; ++i) {
                s1[rt][i] += __shfl_xor(s1[rt][i], m, 64);
                s2[rt][i] += __shfl_xor(s2[rt][i], m, 64);
            }
    if (cl == 0) {
        #pragma unroll
        for (int rt = 0; rt < 4; ++rt)
            #pragma unroll
            for (int i = 0; i < 4; ++i) {
                int row = rt * 16 + q * 4 + i;
                s1a[row * 8 + w] = s1[rt][i];
                s2a[row * 8 + w] = s2[rt][i];
            }
    }
    __syncthreads();  // also separates GEMM1 buf reads from phase-5 buf writes

    // ---- Phase 4: finalize mean/rstd ----
    float mean[4][4], rstd[4][4];
    #pragma unroll
    for (int rt = 0; rt < 4; ++rt)
        #pragma unroll
        for (int i = 0; i < 4; ++i) {
            int row = rt * 16 + q * 4 + i;
            float a = 0.f, bb = 0.f;
            #pragma unroll
            for (int k = 0; k < 8; ++k) {
                a += s1a[row * 8 + k];
                bb += s2a[row * 8 + k];
            }
            float mu = a * (1.f / HID);
            float var = bb * (1.f / HID) - mu * mu;
            mean[rt][i] = mu;
            rstd[rt][i] = rsqrtf(var + 1e-5f);
        }

    // ---- Phase 5: LN + GELU + repack as bf16 A-fragments (xact[64][512]) ----
    #pragma unroll
    for (int c = 0; c < 4; ++c) {
        int col = (w * 4 + c) * 16 + cl;
        int kb2 = col >> 5, quad2 = (col >> 3) & 3, j2 = col & 7;
        #pragma unroll
        for (int rt = 0; rt < 4; ++rt)
            #pragma unroll
            for (int i = 0; i < 4; ++i) {
                float x = (acc[rt][c][i] - mean[rt][i]) * rstd[rt][i] * gv[c] + bv[c];
                float g = 0.5f * x * (1.f + erff(x * 0.70710678118654752f));
                int la = swz((q * 4 + i) | (quad2 << 4));
                buf[((rt * 16 + kb2) * 64 + la) * 8 + j2] = (short)f2bf(g);
            }
    }
    __syncthreads();

    // ---- Phase 6: GEMM2: out-slice = xact(64x512) @ W2(512x256) ----
    f32x4 acc2[4][2];
    #pragma unroll
    for (int rt = 0; rt < 4; ++rt)
        #pragma unroll
        for (int c = 0; c < 2; ++c) acc2[rt][c] = (f32x4)(0.f);
    #pragma unroll 2
    for (int kb = 0; kb < 16; ++kb) {
        short8 a[4];
        #pragma unroll
        for (int rt = 0; rt < 4; ++rt) a[rt] = *(const short8*)&buf[((rt * 16 + kb) * 64 + lF) * 8];
        #pragma unroll
        for (int c = 0; c < 2; ++c) {
            const short8 bfr = *(const short8*)(w2p + (((size_t)(w * 2 + c) * 16 + kb) * 64 + l) * 8);
            #pragma unroll
            for (int rt = 0; rt < 4; ++rt)
                acc2[rt][c] = __builtin_amdgcn_mfma_f32_16x16x32_bf16(a[rt], bfr, acc2[rt][c], 0, 0, 0);
        }
    }

    // ---- Phase 7: bias + store ----
    float b2v[2];
    #pragma unroll
    for (int c = 0; c < 2; ++c) b2v[c] = b2[(w * 2 + c) * 16 + cl];
    #pragma unroll
    for (int rt = 0; rt < 4; ++rt)
        #pragma unroll
        for (int c = 0; c < 2; ++c)
            #pragma unroll
            for (int i = 0; i < 4; ++i) {
                long g = g0 + rt * 16 + q * 4 + i;
                out[g * OUTD + (w * 2 + c) * 16 + cl] = acc2[rt][c][i] + b2v[c];
            }
}

// ---------------- launch ----------------

extern "C" void kernel_launch(void* const* d_in, const int* in_sizes, int n_in, void* d_out, int out_size,
                              void* d_ws, size_t ws_size, hipStream_t stream) {
    const int* ei = (const int*)d_in[0];
    const float* P = (const float*)d_in[2];
    const float* emb = (const float*)d_in[3];
    const float* W1 = (const float*)d_in[4];
    const float* b1 = (const float*)d_in[5];
    const float* gamma = (const float*)d_in[6];
    const float* beta = (const float*)d_in[7];
    const float* W2 = (const float*)d_in[8];
    const float* b2 = (const float*)d_in[9];
    float* out = (float*)d_out;

    char* ws = (char*)d_ws;
    size_t off = 0;
    auto alloc = [&](size_t bytes) -> char* {
        char* p = ws + off;
        off += (bytes + 1023) & ~(size_t)1023;
        return p;
    };
    int* idx = (int*)alloc((size_t)NN * 4);
    int* counts = (int*)alloc((size_t)BG * NN * 4);
    int* row_ptr = (int*)alloc((size_t)BG * (NN + 1) * 4);
    int* cursor = (int*)alloc((size_t)BG * NN * 4);
    int* col_sorted = (int*)alloc((size_t)BG * EE * 4);
    short* w1p = (short*)alloc((size_t)131072 * 2);
    short* w2p = (short*)alloc((size_t)131072 * 2);
    float* H = (float*)alloc((size_t)NHOPS * BG * NN * DD * 4);

    hipLaunchKernelGGL(zero_kernel, dim3((BG * NN + 255) / 256), dim3(256), 0, stream, counts, BG * NN);
    hipLaunchKernelGGL(argmax_kernel, dim3((NN + 255) / 256), dim3(256), 0, stream, P, idx);
    hipLaunchKernelGGL(hist_kernel, dim3(BG * EE / 256), dim3(256), 0, stream, ei, counts);
    hipLaunchKernelGGL(scan_kernel, dim3(BG), dim3(256), 0, stream, counts, row_ptr, cursor);
    hipLaunchKernelGGL(scatter_kernel, dim3(BG * EE / 256), dim3(256), 0, stream, ei, cursor, col_sorted);
    hipLaunchKernelGGL(pack_w1_kernel, dim3(512), dim3(256), 0, stream, W1, w1p);
    hipLaunchKernelGGL(pack_w2_kernel, dim3(512), dim3(256), 0, stream, W2, w2p);

    const long hs = (long)BG * NN * DD;
    hipLaunchKernelGGL(spmm_first_kernel, dim3(BG * NN / 4), dim3(256), 0, stream, idx, emb, row_ptr, col_sorted, H);
    for (int h = 1; h < NHOPS; ++h) {
        hipLaunchKernelGGL(spmm_kernel, dim3(BG * NN / 4), dim3(256), 0, stream, H + (long)(h - 1) * hs, row_ptr,
                           col_sorted, H + (long)h * hs);
    }
    hipLaunchKernelGGL(mlp_mfma_kernel, dim3(BG * NN / 64), dim3(512), 0, stream, H, w1p, b1, gamma, beta, w2p, b2,
                       out);
}

// Round 2
// 1317.348 us; speedup vs baseline: 1.0972x; 1.0972x over previous
//
#include <hip/hip_runtime.h>
#include <math.h>

#define BG 8
#define NN 20000
#define EE 320000
#define CC 128
#define DD 64
#define NHOPS 4
#define HID 512
#define OUTD 256

typedef __attribute__((ext_vector_type(8))) short short8;
typedef __attribute__((ext_vector_type(4))) float f32x4;

__device__ __forceinline__ unsigned short f2bf(float f) {
    unsigned u = __float_as_uint(f);
    u += 0x7fffu + ((u >> 16) & 1u);  // RNE
    return (unsigned short)(u >> 16);
}

// LDS lane swizzle: spread epilogue-repack writes across banks.
// bit0 ^= bit4, bit1 ^= bit3. Involution => bijection.
__device__ __forceinline__ int swz(int la) {
    return la ^ ((la >> 4) & 1) ^ (((la >> 3) & 1) << 1);
}

// ---------------- small prep kernels ----------------

__global__ __launch_bounds__(256) void zero_kernel(int* __restrict__ p, int n) {
    int i = blockIdx.x * 256 + threadIdx.x;
    if (i < n) p[i] = 0;
}

__global__ __launch_bounds__(256) void argmax_kernel(const float* __restrict__ P, int* __restrict__ idx) {
    int n = blockIdx.x * 256 + threadIdx.x;
    if (n >= NN) return;
    float best = P[n];
    int bi = 0;
    #pragma unroll 4
    for (int c = 1; c < CC; ++c) {
        float v = P[c * NN + n];
        if (v > best) { best = v; bi = c; }
    }
    idx[n] = bi;
}

__global__ __launch_bounds__(256) void hist_kernel(const int* __restrict__ ei, int* __restrict__ counts) {
    int i = blockIdx.x * 256 + threadIdx.x;
    int b = i / EE, e = i - b * EE;
    int row = ei[(long)b * 2 * EE + e];
    atomicAdd(&counts[b * NN + row], 1);
}

__global__ __launch_bounds__(256) void scan_kernel(const int* __restrict__ counts, int* __restrict__ row_ptr,
                                                   int* __restrict__ cursor) {
    const int b = blockIdx.x, t = threadIdx.x;
    const int CH = (NN + 255) / 256;
    const int* cnt = counts + b * NN;
    int s0 = t * CH, s1 = min(s0 + CH, NN);
    int sum = 0;
    for (int i = s0; i < s1; ++i) sum += cnt[i];
    __shared__ int ss[256];
    ss[t] = sum;
    __syncthreads();
    for (int off = 1; off < 256; off <<= 1) {
        int v = (t >= off) ? ss[t - off] : 0;
        __syncthreads();
        ss[t] += v;
        __syncthreads();
    }
    int run = ss[t] - sum;
    int* rp = row_ptr + b * (NN + 1);
    int* cur = cursor + b * NN;
    for (int i = s0; i < s1; ++i) {
        rp[i] = run;
        cur[i] = run;
        run += cnt[i];
    }
    if (t == 255) rp[NN] = ss[255];
}

__global__ __launch_bounds__(256) void scatter_kernel(const int* __restrict__ ei, int* __restrict__ cursor,
                                                      int* __restrict__ col_sorted) {
    int i = blockIdx.x * 256 + threadIdx.x;
    int b = i / EE, e = i - b * EE;
    const int* eb = ei + (long)b * 2 * EE;
    int row = eb[e], col = eb[EE + e];
    int pos = atomicAdd(&cursor[b * NN + row], 1);
    col_sorted[(long)b * EE + pos] = col;
}

// ---------------- SPMM ----------------
// One wave per node. lane = (e4 = lane>>4 edge slot, d4 = lane&15 float4 slot).
// 4 independent gather chains per wave; float4 (16B) row loads; shfl reduce at end.
// XCD pinning: blockIdx.x & 7 = graph b => graph b's gather working set (5.12 MB)
// stays (mostly) in XCD b's 4 MB L2 instead of bouncing to L3.

// Hop 1: H1[n] = sum_cols emb[idx[col]] — gather the 32 KB table (L1-resident),
// not the 5 MB materialized init_emb.
__global__ __launch_bounds__(256) void spmm_first_kernel(const int* __restrict__ idx, const float* __restrict__ emb,
                                                         const int* __restrict__ row_ptr,
                                                         const int* __restrict__ col_sorted,
                                                         float* __restrict__ Hout) {
    int wave = threadIdx.x >> 6, lane = threadIdx.x & 63;
    int b = blockIdx.x & 7;
    int n = (blockIdx.x >> 3) * 4 + wave;
    const int* rp = row_ptr + b * (NN + 1);
    int s = rp[n], e = rp[n + 1];
    const int* cs = col_sorted + (long)b * EE;
    int e4 = lane >> 4, d4 = lane & 15;
    f32x4 sum = (f32x4)(0.f);
    for (int j = s + e4; j < e; j += 4) {
        int cell = idx[cs[j]];
        sum += *(const f32x4*)&emb[(size_t)cell * DD + d4 * 4];
    }
    #pragma unroll
    for (int i = 0; i < 4; ++i) {
        sum[i] += __shfl_xor(sum[i], 16, 64);
        sum[i] += __shfl_xor(sum[i], 32, 64);
    }
    if (lane < 16) *(f32x4*)&Hout[((long)b * NN + n) * DD + d4 * 4] = sum;
}

__global__ __launch_bounds__(256) void spmm_kernel(const float* __restrict__ Hin,
                                                   const int* __restrict__ row_ptr,
                                                   const int* __restrict__ col_sorted, float* __restrict__ Hout) {
    int wave = threadIdx.x >> 6, lane = threadIdx.x & 63;
    int b = blockIdx.x & 7;
    int n = (blockIdx.x >> 3) * 4 + wave;
    const int* rp = row_ptr + b * (NN + 1);
    int s = rp[n], e = rp[n + 1];
    const float* hb = Hin + (long)b * (NN * DD);
    const int* cs = col_sorted + (long)b * EE;
    int e4 = lane >> 4, d4 = lane & 15;
    f32x4 sum = (f32x4)(0.f);
    for (int j = s + e4; j < e; j += 4) {
        int col = cs[j];
        sum += *(const f32x4*)&hb[(size_t)col * DD + d4 * 4];
    }
    #pragma unroll
    for (int i = 0; i < 4; ++i) {
        sum[i] += __shfl_xor(sum[i], 16, 64);
        sum[i] += __shfl_xor(sum[i], 32, 64);
    }
    if (lane < 16) *(f32x4*)&Hout[((long)b * NN + n) * DD + d4 * 4] = sum;
}

// ---------------- weight packing: bf16 B-fragment layout ----------------
// Omega is staged HOP-MAJOR: k' = h*64 + d. Compensate by permuting W1 rows here:
// fragment k' maps to original W1 row k = d*4 + h.
__global__ __launch_bounds__(256) void pack_w1_kernel(const float* __restrict__ W1, short* __restrict__ w1p) {
    int i = blockIdx.x * 256 + threadIdx.x;  // < 131072
    int j = i & 7, la = (i >> 3) & 63, kb = (i >> 9) & 7, ct = i >> 12;
    int kp = kb * 32 + ((la >> 4) & 3) * 8 + j;  // k' in [0,256), hop-major
    int h = kp >> 6, d = kp & 63;
    int k = d * 4 + h;  // reference W1 row (stack(...,-1).reshape => k = d*HOPS+h)
    int col = ct * 16 + (la & 15);
    w1p[i] = (short)f2bf(W1[k * HID + col]);
}

// W2 packed: i = ((ct*16+kb)*64+la)*8+j (unchanged ordering)
__global__ __launch_bounds__(256) void pack_w2_kernel(const float* __restrict__ W2, short* __restrict__ w2p) {
    int i = blockIdx.x * 256 + threadIdx.x;  // < 131072
    int j = i & 7, la = (i >> 3) & 63, kb = (i >> 9) & 15, ct = i >> 13;
    int k = kb * 32 + ((la >> 4) & 3) * 8 + j;
    int col = ct * 16 + (la & 15);
    w2p[i] = (short)f2bf(W2[k * OUTD + col]);
}

// ---------------- fused MFMA MLP ----------------
// 64 rows/block, 512 threads (8 waves): wave w owns GEMM1 cols [w*64,w*64+64),
// GEMM2 cols [w*32,w*32+32).
// __launch_bounds__(512, 2): min 2 BLOCKS/CU (CUDA-style semantics, verified
// empirically: (512,4) produced a 64-VGPR cap = 8 waves/SIMD and catastrophic
// spills, 1.9 GB scratch traffic). (512,2) => 16 waves/CU = 4 waves/SIMD =>
// 128-reg budget, which this structure's acc diet (64 + 32 AGPR, disjoint
// lifetimes) was designed for.
__global__ __launch_bounds__(512, 2) void mlp_mfma_kernel(const float* __restrict__ H,  // [hop][b][n][d]
                                                          const short* __restrict__ w1p,
                                                          const float* __restrict__ b1,
                                                          const float* __restrict__ gamma,
                                                          const float* __restrict__ beta,
                                                          const short* __restrict__ w2p,
                                                          const float* __restrict__ b2, float* __restrict__ out) {
    __shared__ short buf[32768];   // 64 KB: omega frags (32 KB) then xact frags (64 KB)
    __shared__ float s1a[64 * 8];  // LN partials, separate so no extra barrier
    __shared__ float s2a[64 * 8];
    const int t = threadIdx.x;
    const int w = t >> 6, l = t & 63;
    const int q = l >> 4, cl = l & 15;
    const int lF = swz(l);
    const long g0 = (long)blockIdx.x * 64;

    // ---- Phase 1: stage omega[64][256] (k' = h*64+d) as bf16 A-fragments ----
    // Per chunk: 8 consecutive d of one hop plane = 32B contiguous global,
    // one 16B fragment slot in LDS.
    {
        const int rsub = l >> 3, oct = l & 7;
        #pragma unroll
        for (int i = 0; i < 4; ++i) {
            int task = i * 8 + w;  // 32 tasks = 4 hops x 8 row-groups
            int h = task >> 3, rg = task & 7;
            int r = rg * 8 + rsub;
            const float* src = H + ((long)h * (BG * NN) + g0 + r) * DD + oct * 8;
            f32x4 v0 = *(const f32x4*)src;
            f32x4 v1 = *(const f32x4*)(src + 4);
            short8 frag;
            frag[0] = (short)f2bf(v0[0]);
            frag[1] = (short)f2bf(v0[1]);
            frag[2] = (short)f2bf(v0[2]);
            frag[3] = (short)f2bf(v0[3]);
            frag[4] = (short)f2bf(v1[0]);
            frag[5] = (short)f2bf(v1[1]);
            frag[6] = (short)f2bf(v1[2]);
            frag[7] = (short)f2bf(v1[3]);
            int kb = (h << 1) | (oct >> 2);  // k0 = h*64+oct*8; kb = k0>>5
            int quad = oct & 3;
            int rt = r >> 4;
            int la = (r & 15) | (quad << 4);
            *(short8*)&buf[((rt * 8 + kb) * 64 + swz(la)) * 8] = frag;
        }
    }
    __syncthreads();

    // ---- Phase 2: GEMM1: acc[rt][c] = omega(64x256) @ W1(256x512) wave-slice ----
    f32x4 acc[4][4];
    #pragma unroll
    for (int rt = 0; rt < 4; ++rt)
        #pragma unroll
        for (int c = 0; c < 4; ++c) acc[rt][c] = (f32x4)(0.f);
    #pragma unroll 2
    for (int kb = 0; kb < 8; ++kb) {
        short8 a[4];
        #pragma unroll
        for (int rt = 0; rt < 4; ++rt) a[rt] = *(const short8*)&buf[((rt * 8 + kb) * 64 + lF) * 8];
        #pragma unroll
        for (int c = 0; c < 4; ++c) {
            const short8 bfr = *(const short8*)(w1p + (((size_t)(w * 4 + c) * 8 + kb) * 64 + l) * 8);
            #pragma unroll
            for (int rt = 0; rt < 4; ++rt)
                acc[rt][c] = __builtin_amdgcn_mfma_f32_16x16x32_bf16(a[rt], bfr, acc[rt][c], 0, 0, 0);
        }
    }

    // ---- Phase 3: bias + row partial sums -> LDS ----
    float b1v[4], gv[4], bv[4];
    #pragma unroll
    for (int c = 0; c < 4; ++c) {
        int col = (w * 4 + c) * 16 + cl;
        b1v[c] = b1[col];
        gv[c] = gamma[col];
        bv[c] = beta[col];
    }
    float s1[4][4], s2[4][4];
    #pragma unroll
    for (int rt = 0; rt < 4; ++rt)
        #pragma unroll
        for (int i = 0; i < 4; ++i) {
            float a = 0.f, bb = 0.f;
            #pragma unroll
            for (int c = 0; c < 4; ++c) {
                float x = acc[rt][c][i] + b1v[c];
                acc[rt][c][i] = x;
                a += x;
                bb += x * x;
            }
            s1[rt][i] = a;
            s2[rt][i] = bb;
        }
    #pragma unroll
    for (int m = 1; m < 16; m <<= 1)
        #pragma unroll
        for (int rt = 0; rt < 4; ++rt)
            #pragma unroll
            for (int i = 0; i < 4; ++i) {
                s1[rt][i] += __shfl_xor(s1[rt][i], m, 64);
                s2[rt][i] += __shfl_xor(s2[rt][i], m, 64);
            }
    if (cl == 0) {
        #pragma unroll
        for (int rt = 0; rt < 4; ++rt)
            #pragma unroll
            for (int i = 0; i < 4; ++i) {
                int row = rt * 16 + q * 4 + i;
                s1a[row * 8 + w] = s1[rt][i];
                s2a[row * 8 + w] = s2[rt][i];
            }
    }
    __syncthreads();  // also separates GEMM1 buf reads from phase-5 buf writes

    // ---- Phase 4: finalize mean/rstd ----
    float mean[4][4], rstd[4][4];
    #pragma unroll
    for (int rt = 0; rt < 4; ++rt)
        #pragma unroll
        for (int i = 0; i < 4; ++i) {
            int row = rt * 16 + q * 4 + i;
            float a = 0.f, bb = 0.f;
            #pragma unroll
            for (int k = 0; k < 8; ++k) {
                a += s1a[row * 8 + k];
                bb += s2a[row * 8 + k];
            }
            float mu = a * (1.f / HID);
            float var = bb * (1.f / HID) - mu * mu;
            mean[rt][i] = mu;
            rstd[rt][i] = rsqrtf(var + 1e-5f);
        }

    // ---- Phase 5: LN + GELU + repack as bf16 A-fragments (xact[64][512]) ----
    #pragma unroll
    for (int c = 0; c < 4; ++c) {
        int col = (w * 4 + c) * 16 + cl;
        int kb2 = col >> 5, quad2 = (col >> 3) & 3, j2 = col & 7;
        #pragma unroll
        for (int rt = 0; rt < 4; ++rt)
            #pragma unroll
            for (int i = 0; i < 4; ++i) {
                float x = (acc[rt][c][i] - mean[rt][i]) * rstd[rt][i] * gv[c] + bv[c];
                float g = 0.5f * x * (1.f + erff(x * 0.70710678118654752f));
                int la = swz((q * 4 + i) | (quad2 << 4));
                buf[((rt * 16 + kb2) * 64 + la) * 8 + j2] = (short)f2bf(g);
            }
    }
    __syncthreads();

    // ---- Phase 6: GEMM2: out-slice = xact(64x512) @ W2(512x256) ----
    f32x4 acc2[4][2];
    #pragma unroll
    for (int rt = 0; rt < 4; ++rt)
        #pragma unroll
        for (int c = 0; c < 2; ++c) acc2[rt][c] = (f32x4)(0.f);
    #pragma unroll 2
    for (int kb = 0; kb < 16; ++kb) {
        short8 a[4];
        #pragma unroll
        for (int rt = 0; rt < 4; ++rt) a[rt] = *(const short8*)&buf[((rt * 16 + kb) * 64 + lF) * 8];
        #pragma unroll
        for (int c = 0; c < 2; ++c) {
            const short8 bfr = *(const short8*)(w2p + (((size_t)(w * 2 + c) * 16 + kb) * 64 + l) * 8);
            #pragma unroll
            for (int rt = 0; rt < 4; ++rt)
                acc2[rt][c] = __builtin_amdgcn_mfma_f32_16x16x32_bf16(a[rt], bfr, acc2[rt][c], 0, 0, 0);
        }
    }

    // ---- Phase 7: bias + store ----
    float b2v[2];
    #pragma unroll
    for (int c = 0; c < 2; ++c) b2v[c] = b2[(w * 2 + c) * 16 + cl];
    #pragma unroll
    for (int rt = 0; rt < 4; ++rt)
        #pragma unroll
        for (int c = 0; c < 2; ++c)
            #pragma unroll
            for (int i = 0; i < 4; ++i) {
                long g = g0 + rt * 16 + q * 4 + i;
                out[g * OUTD + (w * 2 + c) * 16 + cl] = acc2[rt][c][i] + b2v[c];
            }
}

// ---------------- launch ----------------

extern "C" void kernel_launch(void* const* d_in, const int* in_sizes, int n_in, void* d_out, int out_size,
                              void* d_ws, size_t ws_size, hipStream_t stream) {
    const int* ei = (const int*)d_in[0];
    const float* P = (const float*)d_in[2];
    const float* emb = (const float*)d_in[3];
    const float* W1 = (const float*)d_in[4];
    const float* b1 = (const float*)d_in[5];
    const float* gamma = (const float*)d_in[6];
    const float* beta = (const float*)d_in[7];
    const float* W2 = (const float*)d_in[8];
    const float* b2 = (const float*)d_in[9];
    float* out = (float*)d_out;

    char* ws = (char*)d_ws;
    size_t off = 0;
    auto alloc = [&](size_t bytes) -> char* {
        char* p = ws + off;
        off += (bytes + 1023) & ~(size_t)1023;
        return p;
    };
    int* idx = (int*)alloc((size_t)NN * 4);
    int* counts = (int*)alloc((size_t)BG * NN * 4);
    int* row_ptr = (int*)alloc((size_t)BG * (NN + 1) * 4);
    int* cursor = (int*)alloc((size_t)BG * NN * 4);
    int* col_sorted = (int*)alloc((size_t)BG * EE * 4);
    short* w1p = (short*)alloc((size_t)131072 * 2);
    short* w2p = (short*)alloc((size_t)131072 * 2);
    float* H = (float*)alloc((size_t)NHOPS * BG * NN * DD * 4);

    hipLaunchKernelGGL(zero_kernel, dim3((BG * NN + 255) / 256), dim3(256), 0, stream, counts, BG * NN);
    hipLaunchKernelGGL(argmax_kernel, dim3((NN + 255) / 256), dim3(256), 0, stream, P, idx);
    hipLaunchKernelGGL(hist_kernel, dim3(BG * EE / 256), dim3(256), 0, stream, ei, counts);
    hipLaunchKernelGGL(scan_kernel, dim3(BG), dim3(256), 0, stream, counts, row_ptr, cursor);
    hipLaunchKernelGGL(scatter_kernel, dim3(BG * EE / 256), dim3(256), 0, stream, ei, cursor, col_sorted);
    hipLaunchKernelGGL(pack_w1_kernel, dim3(512), dim3(256), 0, stream, W1, w1p);
    hipLaunchKernelGGL(pack_w2_kernel, dim3(512), dim3(256), 0, stream, W2, w2p);

    const long hs = (long)BG * NN * DD;
    hipLaunchKernelGGL(spmm_first_kernel, dim3(BG * NN / 4), dim3(256), 0, stream, idx, emb, row_ptr, col_sorted, H);
    for (int h = 1; h < NHOPS; ++h) {
        hipLaunchKernelGGL(spmm_kernel, dim3(BG * NN / 4), dim3(256), 0, stream, H + (long)(h - 1) * hs, row_ptr,
                           col_sorted, H + (long)h * hs);
    }
    hipLaunchKernelGGL(mlp_mfma_kernel, dim3(BG * NN / 64), dim3(512), 0, stream, H, w1p, b1, gamma, beta, w2p, b2,
                       out);
}

// Round 4
// 1011.413 us; speedup vs baseline: 1.4291x; 1.3025x over previous
//
#include <hip/hip_runtime.h>
#include <math.h>

#define BG 8
#define NN 20000
#define EE 320000
#define CC 128
#define DD 64
#define NHOPS 4
#define HID 512
#define OUTD 256

typedef __attribute__((ext_vector_type(8))) short short8;
typedef __attribute__((ext_vector_type(4))) float f32x4;

__device__ __forceinline__ unsigned short f2bf(float f) {
    unsigned u = __float_as_uint(f);
    u += 0x7fffu + ((u >> 16) & 1u);  // RNE
    return (unsigned short)(u >> 16);
}

// LDS lane swizzle: spread epilogue-repack writes across banks.
// bit0 ^= bit4, bit1 ^= bit3. Involution => bijection.
__device__ __forceinline__ int swz(int la) {
    return la ^ ((la >> 4) & 1) ^ (((la >> 3) & 1) << 1);
}

// ---------------- small prep kernels ----------------

__global__ __launch_bounds__(256) void zero_kernel(int* __restrict__ p, int n) {
    int i = blockIdx.x * 256 + threadIdx.x;
    if (i < n) p[i] = 0;
}

__global__ __launch_bounds__(256) void argmax_kernel(const float* __restrict__ P, int* __restrict__ idx) {
    int n = blockIdx.x * 256 + threadIdx.x;
    if (n >= NN) return;
    float best = P[n];
    int bi = 0;
    #pragma unroll 4
    for (int c = 1; c < CC; ++c) {
        float v = P[c * NN + n];
        if (v > best) { best = v; bi = c; }
    }
    idx[n] = bi;
}

__global__ __launch_bounds__(256) void hist_kernel(const int* __restrict__ ei, int* __restrict__ counts) {
    int i = blockIdx.x * 256 + threadIdx.x;
    int b = i / EE, e = i - b * EE;
    int row = ei[(long)b * 2 * EE + e];
    atomicAdd(&counts[b * NN + row], 1);
}

__global__ __launch_bounds__(256) void scan_kernel(const int* __restrict__ counts, int* __restrict__ row_ptr,
                                                   int* __restrict__ cursor) {
    const int b = blockIdx.x, t = threadIdx.x;
    const int CH = (NN + 255) / 256;
    const int* cnt = counts + b * NN;
    int s0 = t * CH, s1 = min(s0 + CH, NN);
    int sum = 0;
    for (int i = s0; i < s1; ++i) sum += cnt[i];
    __shared__ int ss[256];
    ss[t] = sum;
    __syncthreads();
    for (int off = 1; off < 256; off <<= 1) {
        int v = (t >= off) ? ss[t - off] : 0;
        __syncthreads();
        ss[t] += v;
        __syncthreads();
    }
    int run = ss[t] - sum;
    int* rp = row_ptr + b * (NN + 1);
    int* cur = cursor + b * NN;
    for (int i = s0; i < s1; ++i) {
        rp[i] = run;
        cur[i] = run;
        run += cnt[i];
    }
    if (t == 255) rp[NN] = ss[255];
}

__global__ __launch_bounds__(256) void scatter_kernel(const int* __restrict__ ei, int* __restrict__ cursor,
                                                      int* __restrict__ col_sorted) {
    int i = blockIdx.x * 256 + threadIdx.x;
    int b = i / EE, e = i - b * EE;
    const int* eb = ei + (long)b * 2 * EE;
    int row = eb[e], col = eb[EE + e];
    int pos = atomicAdd(&cursor[b * NN + row], 1);
    col_sorted[(long)b * EE + pos] = col;
}

// ---------------- SPMM ----------------
// One wave per node. lane = (e4 = lane>>4 edge slot, d4 = lane&15 float4 slot).
// 4 independent gather chains per wave; float4 (16B) row loads; shfl reduce at end.
// XCD pinning: blockIdx.x & 7 = graph b => graph b's gather working set (5.12 MB)
// stays (mostly) in XCD b's 4 MB L2 instead of bouncing to L3.

// Hop 1: H1[n] = sum_cols emb[idx[col]] — gather the 32 KB table (L1-resident),
// not a 5 MB materialized init_emb.
__global__ __launch_bounds__(256) void spmm_first_kernel(const int* __restrict__ idx, const float* __restrict__ emb,
                                                         const int* __restrict__ row_ptr,
                                                         const int* __restrict__ col_sorted,
                                                         float* __restrict__ Hout) {
    int wave = threadIdx.x >> 6, lane = threadIdx.x & 63;
    int b = blockIdx.x & 7;
    int n = (blockIdx.x >> 3) * 4 + wave;
    const int* rp = row_ptr + b * (NN + 1);
    int s = rp[n], e = rp[n + 1];
    const int* cs = col_sorted + (long)b * EE;
    int e4 = lane >> 4, d4 = lane & 15;
    f32x4 sum = (f32x4)(0.f);
    for (int j = s + e4; j < e; j += 4) {
        int cell = idx[cs[j]];
        sum += *(const f32x4*)&emb[(size_t)cell * DD + d4 * 4];
    }
    #pragma unroll
    for (int i = 0; i < 4; ++i) {
        sum[i] += __shfl_xor(sum[i], 16, 64);
        sum[i] += __shfl_xor(sum[i], 32, 64);
    }
    if (lane < 16) *(f32x4*)&Hout[((long)b * NN + n) * DD + d4 * 4] = sum;
}

__global__ __launch_bounds__(256) void spmm_kernel(const float* __restrict__ Hin,
                                                   const int* __restrict__ row_ptr,
                                                   const int* __restrict__ col_sorted, float* __restrict__ Hout) {
    int wave = threadIdx.x >> 6, lane = threadIdx.x & 63;
    int b = blockIdx.x & 7;
    int n = (blockIdx.x >> 3) * 4 + wave;
    const int* rp = row_ptr + b * (NN + 1);
    int s = rp[n], e = rp[n + 1];
    const float* hb = Hin + (long)b * (NN * DD);
    const int* cs = col_sorted + (long)b * EE;
    int e4 = lane >> 4, d4 = lane & 15;
    f32x4 sum = (f32x4)(0.f);
    for (int j = s + e4; j < e; j += 4) {
        int col = cs[j];
        sum += *(const f32x4*)&hb[(size_t)col * DD + d4 * 4];
    }
    #pragma unroll
    for (int i = 0; i < 4; ++i) {
        sum[i] += __shfl_xor(sum[i], 16, 64);
        sum[i] += __shfl_xor(sum[i], 32, 64);
    }
    if (lane < 16) *(f32x4*)&Hout[((long)b * NN + n) * DD + d4 * 4] = sum;
}

// ---------------- weight packing: bf16 B-fragment layout ----------------
// Omega is staged HOP-MAJOR: k' = h*64 + d. Compensate by permuting W1 rows here:
// fragment k' maps to original W1 row k = d*4 + h.
__global__ __launch_bounds__(256) void pack_w1_kernel(const float* __restrict__ W1, short* __restrict__ w1p) {
    int i = blockIdx.x * 256 + threadIdx.x;  // < 131072
    int j = i & 7, la = (i >> 3) & 63, kb = (i >> 9) & 7, ct = i >> 12;
    int kp = kb * 32 + ((la >> 4) & 3) * 8 + j;  // k' in [0,256), hop-major
    int h = kp >> 6, d = kp & 63;
    int k = d * 4 + h;  // reference W1 row (stack(...,-1).reshape => k = d*HOPS+h)
    int col = ct * 16 + (la & 15);
    w1p[i] = (short)f2bf(W1[k * HID + col]);
}

// W2 packed: i = ((ct*16+kb)*64+la)*8+j (unchanged ordering)
__global__ __launch_bounds__(256) void pack_w2_kernel(const float* __restrict__ W2, short* __restrict__ w2p) {
    int i = blockIdx.x * 256 + threadIdx.x;  // < 131072
    int j = i & 7, la = (i >> 3) & 63, kb = (i >> 9) & 15, ct = i >> 13;
    int k = kb * 32 + ((la >> 4) & 3) * 8 + j;
    int col = ct * 16 + (la & 15);
    w2p[i] = (short)f2bf(W2[k * OUTD + col]);
}

// ---------------- fused MFMA MLP ----------------
// 32 rows/block, 256 threads (4 waves). Wave w: GEMM1 cols [w*128,w*128+128)
// => acc[2][8] = 64 AGPR; GEMM2 cols [w*64,w*64+64) => acc2[2][4] = 32 AGPR.
// __launch_bounds__(256,4): empirically arg2 = blocks/CU on this toolchain
// ((256,2)->256 regs, (512,4)->64, (512,2)->128). 4 blocks/CU = 16 waves/CU =
// 4 waves/SIMD => 128-reg budget. Peak live set ~110 (acc 64 + s1/s2 16 +
// b1v 8 + addressing): mean/rstd recomputed inline, gamma/beta deferred until
// s1/s2 are dead. LDS: 32 KB buf + 1 KB partials => 4 blocks/CU fits (135 KB).
__global__ __launch_bounds__(256, 4) void mlp_mfma_kernel(const float* __restrict__ H,  // [hop][b][n][d]
                                                          const short* __restrict__ w1p,
                                                          const float* __restrict__ b1,
                                                          const float* __restrict__ gamma,
                                                          const float* __restrict__ beta,
                                                          const short* __restrict__ w2p,
                                                          const float* __restrict__ b2, float* __restrict__ out) {
    __shared__ short buf[16384];   // 32 KB: omega frags (16 KB) then xact frags (32 KB)
    __shared__ float s1a[32 * 4];  // LN partials
    __shared__ float s2a[32 * 4];
    const int t = threadIdx.x;
    const int w = t >> 6, l = t & 63;
    const int q = l >> 4, cl = l & 15;
    const int lF = swz(l);
    const long g0 = (long)blockIdx.x * 32;

    // ---- Phase 1: stage omega[32][256] (k' = h*64+d) as bf16 A-fragments ----
    // Per chunk: 8 consecutive d of one hop plane = 32B contiguous global,
    // one 16B fragment slot in LDS. 16 tasks = 4 hops x 4 row-groups.
    {
        const int rsub = l >> 3, oct = l & 7;
        #pragma unroll
        for (int i = 0; i < 4; ++i) {
            int task = i * 4 + w;
            int h = task >> 2, rg = task & 3;
            int r = rg * 8 + rsub;
            const float* src = H + ((long)h * (BG * NN) + g0 + r) * DD + oct * 8;
            f32x4 v0 = *(const f32x4*)src;
            f32x4 v1 = *(const f32x4*)(src + 4);
            short8 frag;
            frag[0] = (short)f2bf(v0[0]);
            frag[1] = (short)f2bf(v0[1]);
            frag[2] = (short)f2bf(v0[2]);
            frag[3] = (short)f2bf(v0[3]);
            frag[4] = (short)f2bf(v1[0]);
            frag[5] = (short)f2bf(v1[1]);
            frag[6] = (short)f2bf(v1[2]);
            frag[7] = (short)f2bf(v1[3]);
            int kb = (h << 1) | (oct >> 2);  // k0 = h*64+oct*8; kb = k0>>5
            int quad = oct & 3;
            int rt = r >> 4;
            int la = (r & 15) | (quad << 4);
            *(short8*)&buf[((rt * 8 + kb) * 64 + swz(la)) * 8] = frag;
        }
    }
    __syncthreads();

    // ---- Phase 2: GEMM1: acc[rt][c] = omega(32x256) @ W1(256x512) wave-slice ----
    f32x4 acc[2][8];
    #pragma unroll
    for (int rt = 0; rt < 2; ++rt)
        #pragma unroll
        for (int c = 0; c < 8; ++c) acc[rt][c] = (f32x4)(0.f);
    #pragma unroll 2
    for (int kb = 0; kb < 8; ++kb) {
        short8 a[2];
        #pragma unroll
        for (int rt = 0; rt < 2; ++rt) a[rt] = *(const short8*)&buf[((rt * 8 + kb) * 64 + lF) * 8];
        #pragma unroll
        for (int c = 0; c < 8; ++c) {
            const short8 bfr = *(const short8*)(w1p + (((size_t)(w * 8 + c) * 8 + kb) * 64 + l) * 8);
            #pragma unroll
            for (int rt = 0; rt < 2; ++rt)
                acc[rt][c] = __builtin_amdgcn_mfma_f32_16x16x32_bf16(a[rt], bfr, acc[rt][c], 0, 0, 0);
        }
    }

    // ---- Phase 3: bias + row partial sums -> LDS ----
    {
        float b1v[8];
        #pragma unroll
        for (int c = 0; c < 8; ++c) b1v[c] = b1[(w * 8 + c) * 16 + cl];
        float s1[2][4], s2[2][4];
        #pragma unroll
        for (int rt = 0; rt < 2; ++rt)
            #pragma unroll
            for (int i = 0; i < 4; ++i) {
                float a = 0.f, bb = 0.f;
                #pragma unroll
                for (int c = 0; c < 8; ++c) {
                    float x = acc[rt][c][i] + b1v[c];
                    acc[rt][c][i] = x;
                    a += x;
                    bb += x * x;
                }
                s1[rt][i] = a;
                s2[rt][i] = bb;
            }
        #pragma unroll
        for (int m = 1; m < 16; m <<= 1)
            #pragma unroll
            for (int rt = 0; rt < 2; ++rt)
                #pragma unroll
                for (int i = 0; i < 4; ++i) {
                    s1[rt][i] += __shfl_xor(s1[rt][i], m, 64);
                    s2[rt][i] += __shfl_xor(s2[rt][i], m, 64);
                }
        if (cl == 0) {
            #pragma unroll
            for (int rt = 0; rt < 2; ++rt)
                #pragma unroll
                for (int i = 0; i < 4; ++i) {
                    int row = rt * 16 + q * 4 + i;
                    s1a[row * 4 + w] = s1[rt][i];
                    s2a[row * 4 + w] = s2[rt][i];
                }
        }
    }
    __syncthreads();  // partials visible; also separates GEMM1 buf reads from phase-5 buf writes

    // ---- Phase 5: LN (stats inline from LDS partials) + GELU + repack bf16 A-frags ----
    {
        float gv[8], bv[8];
        #pragma unroll
        for (int c = 0; c < 8; ++c) {
            int col = (w * 8 + c) * 16 + cl;
            gv[c] = gamma[col];
            bv[c] = beta[col];
        }
        #pragma unroll
        for (int rt = 0; rt < 2; ++rt)
            #pragma unroll
            for (int i = 0; i < 4; ++i) {
                int row = rt * 16 + q * 4 + i;
                float a = s1a[row * 4] + s1a[row * 4 + 1] + s1a[row * 4 + 2] + s1a[row * 4 + 3];
                float bb = s2a[row * 4] + s2a[row * 4 + 1] + s2a[row * 4 + 2] + s2a[row * 4 + 3];
                float mu = a * (1.f / HID);
                float var = bb * (1.f / HID) - mu * mu;
                float rs = rsqrtf(var + 1e-5f);
                #pragma unroll
                for (int c = 0; c < 8; ++c) {
                    int col = (w * 8 + c) * 16 + cl;
                    int kb2 = col >> 5, quad2 = (col >> 3) & 3, j2 = col & 7;
                    float x = (acc[rt][c][i] - mu) * rs * gv[c] + bv[c];
                    float g = 0.5f * x * (1.f + erff(x * 0.70710678118654752f));
                    int la = swz((q * 4 + i) | (quad2 << 4));
                    buf[((rt * 16 + kb2) * 64 + la) * 8 + j2] = (short)f2bf(g);
                }
            }
    }
    __syncthreads();

    // ---- Phase 6: GEMM2: out-slice = xact(32x512) @ W2(512x256) ----
    f32x4 acc2[2][4];
    #pragma unroll
    for (int rt = 0; rt < 2; ++rt)
        #pragma unroll
        for (int c = 0; c < 4; ++c) acc2[rt][c] = (f32x4)(0.f);
    #pragma unroll 2
    for (int kb = 0; kb < 16; ++kb) {
        short8 a[2];
        #pragma unroll
        for (int rt = 0; rt < 2; ++rt) a[rt] = *(const short8*)&buf[((rt * 16 + kb) * 64 + lF) * 8];
        #pragma unroll
        for (int c = 0; c < 4; ++c) {
            const short8 bfr = *(const short8*)(w2p + (((size_t)(w * 4 + c) * 16 + kb) * 64 + l) * 8);
            #pragma unroll
            for (int rt = 0; rt < 2; ++rt)
                acc2[rt][c] = __builtin_amdgcn_mfma_f32_16x16x32_bf16(a[rt], bfr, acc2[rt][c], 0, 0, 0);
        }
    }

    // ---- Phase 7: bias + store ----
    float b2v[4];
    #pragma unroll
    for (int c = 0; c < 4; ++c) b2v[c] = b2[(w * 4 + c) * 16 + cl];
    #pragma unroll
    for (int rt = 0; rt < 2; ++rt)
        #pragma unroll
        for (int c = 0; c < 4; ++c)
            #pragma unroll
            for (int i = 0; i < 4; ++i) {
                long g = g0 + rt * 16 + q * 4 + i;
                out[g * OUTD + (w * 4 + c) * 16 + cl] = acc2[rt][c][i] + b2v[c];
            }
}

// ---------------- launch ----------------

extern "C" void kernel_launch(void* const* d_in, const int* in_sizes, int n_in, void* d_out, int out_size,
                              void* d_ws, size_t ws_size, hipStream_t stream) {
    const int* ei = (const int*)d_in[0];
    const float* P = (const float*)d_in[2];
    const float* emb = (const float*)d_in[3];
    const float* W1 = (const float*)d_in[4];
    const float* b1 = (const float*)d_in[5];
    const float* gamma = (const float*)d_in[6];
    const float* beta = (const float*)d_in[7];
    const float* W2 = (const float*)d_in[8];
    const float* b2 = (const float*)d_in[9];
    float* out = (float*)d_out;

    char* ws = (char*)d_ws;
    size_t off = 0;
    auto alloc = [&](size_t bytes) -> char* {
        char* p = ws + off;
        off += (bytes + 1023) & ~(size_t)1023;
        return p;
    };
    int* idx = (int*)alloc((size_t)NN * 4);
    int* counts = (int*)alloc((size_t)BG * NN * 4);
    int* row_ptr = (int*)alloc((size_t)BG * (NN + 1) * 4);
    int* cursor = (int*)alloc((size_t)BG * NN * 4);
    int* col_sorted = (int*)alloc((size_t)BG * EE * 4);
    short* w1p = (short*)alloc((size_t)131072 * 2);
    short* w2p = (short*)alloc((size_t)131072 * 2);
    float* H = (float*)alloc((size_t)NHOPS * BG * NN * DD * 4);

    hipLaunchKernelGGL(zero_kernel, dim3((BG * NN + 255) / 256), dim3(256), 0, stream, counts, BG * NN);
    hipLaunchKernelGGL(argmax_kernel, dim3((NN + 255) / 256), dim3(256), 0, stream, P, idx);
    hipLaunchKernelGGL(hist_kernel, dim3(BG * EE / 256), dim3(256), 0, stream, ei, counts);
    hipLaunchKernelGGL(scan_kernel, dim3(BG), dim3(256), 0, stream, counts, row_ptr, cursor);
    hipLaunchKernelGGL(scatter_kernel, dim3(BG * EE / 256), dim3(256), 0, stream, ei, cursor, col_sorted);
    hipLaunchKernelGGL(pack_w1_kernel, dim3(512), dim3(256), 0, stream, W1, w1p);
    hipLaunchKernelGGL(pack_w2_kernel, dim3(512), dim3(256), 0, stream, W2, w2p);

    const long hs = (long)BG * NN * DD;
    hipLaunchKernelGGL(spmm_first_kernel, dim3(BG * NN / 4), dim3(256), 0, stream, idx, emb, row_ptr, col_sorted, H);
    for (int h = 1; h < NHOPS; ++h) {
        hipLaunchKernelGGL(spmm_kernel, dim3(BG * NN / 4), dim3(256), 0, stream, H + (long)(h - 1) * hs, row_ptr,
                           col_sorted, H + (long)h * hs);
    }
    hipLaunchKernelGGL(mlp_mfma_kernel, dim3(BG * NN / 32), dim3(256), 0, stream, H, w1p, b1, gamma, beta, w2p, b2,
                       out);
}

// Round 6
// 924.703 us; speedup vs baseline: 1.5631x; 1.0938x over previous
//
#include <hip/hip_runtime.h>
#include <math.h>

#define BG 8
#define NN 20000
#define EE 320000
#define CC 128
#define DD 64
#define NHOPS 4
#define HID 512
#define OUTD 256

typedef __attribute__((ext_vector_type(8))) short short8;
typedef __attribute__((ext_vector_type(4))) short s16x4;
typedef __attribute__((ext_vector_type(4))) float f32x4;

__device__ __forceinline__ unsigned short f2bf(float f) {
    unsigned u = __float_as_uint(f);
    u += 0x7fffu + ((u >> 16) & 1u);  // RNE
    return (unsigned short)(u >> 16);
}

__device__ __forceinline__ float bf2f(unsigned short u) {
    return __uint_as_float(((unsigned)u) << 16);
}

// LDS lane swizzle: spread epilogue-repack writes across banks.
// bit0 ^= bit4, bit1 ^= bit3. Involution => bijection.
__device__ __forceinline__ int swz(int la) {
    return la ^ ((la >> 4) & 1) ^ (((la >> 3) & 1) << 1);
}

// ---------------- small prep kernels ----------------

__global__ __launch_bounds__(256) void zero_kernel(int* __restrict__ p, int n) {
    int i = blockIdx.x * 256 + threadIdx.x;
    if (i < n) p[i] = 0;
}

__global__ __launch_bounds__(256) void argmax_kernel(const float* __restrict__ P, int* __restrict__ idx) {
    int n = blockIdx.x * 256 + threadIdx.x;
    if (n >= NN) return;
    float best = P[n];
    int bi = 0;
    #pragma unroll 4
    for (int c = 1; c < CC; ++c) {
        float v = P[c * NN + n];
        if (v > best) { best = v; bi = c; }
    }
    idx[n] = bi;
}

__global__ __launch_bounds__(256) void hist_kernel(const int* __restrict__ ei, int* __restrict__ counts) {
    int i = blockIdx.x * 256 + threadIdx.x;
    int b = i / EE, e = i - b * EE;
    int row = ei[(long)b * 2 * EE + e];
    atomicAdd(&counts[b * NN + row], 1);
}

__global__ __launch_bounds__(256) void scan_kernel(const int* __restrict__ counts, int* __restrict__ row_ptr,
                                                   int* __restrict__ cursor) {
    const int b = blockIdx.x, t = threadIdx.x;
    const int CH = (NN + 255) / 256;
    const int* cnt = counts + b * NN;
    int s0 = t * CH, s1 = min(s0 + CH, NN);
    int sum = 0;
    for (int i = s0; i < s1; ++i) sum += cnt[i];
    __shared__ int ss[256];
    ss[t] = sum;
    __syncthreads();
    for (int off = 1; off < 256; off <<= 1) {
        int v = (t >= off) ? ss[t - off] : 0;
        __syncthreads();
        ss[t] += v;
        __syncthreads();
    }
    int run = ss[t] - sum;
    int* rp = row_ptr + b * (NN + 1);
    int* cur = cursor + b * NN;
    for (int i = s0; i < s1; ++i) {
        rp[i] = run;
        cur[i] = run;
        run += cnt[i];
    }
    if (t == 255) rp[NN] = ss[255];
}

__global__ __launch_bounds__(256) void scatter_kernel(const int* __restrict__ ei, int* __restrict__ cursor,
                                                      int* __restrict__ col_sorted) {
    int i = blockIdx.x * 256 + threadIdx.x;
    int b = i / EE, e = i - b * EE;
    const int* eb = ei + (long)b * 2 * EE;
    int row = eb[e], col = eb[EE + e];
    int pos = atomicAdd(&cursor[b * NN + row], 1);
    col_sorted[(long)b * EE + pos] = col;
}

// ---------------- SPMM ----------------
// H stored in BF16: halves gather bytes (row = 128 B) and shrinks the per-graph
// working set to 2.56 MB => fits the 4 MB per-XCD L2 (round-4 counters showed
// fp32's 5.12 MB working set thrashing L2; gathers ran at L3 speed, ~170 us/hop).
// Accumulate fp32, round once on store (RNE).
// XCD pinning: blockIdx.x & 7 = graph b keeps graph b's rows in one L2.

// Hop 1: H1[n] = sum_cols emb[idx[col]] — gather the 32 KB fp32 table
// (L1-resident) through idx; 4 edge slots x 16 lanes x 16 B.
__global__ __launch_bounds__(256) void spmm_first_kernel(const int* __restrict__ idx, const float* __restrict__ emb,
                                                         const int* __restrict__ row_ptr,
                                                         const int* __restrict__ col_sorted,
                                                         short* __restrict__ Hout) {
    int wave = threadIdx.x >> 6, lane = threadIdx.x & 63;
    int b = blockIdx.x & 7;
    int n = (blockIdx.x >> 3) * 4 + wave;
    const int* rp = row_ptr + b * (NN + 1);
    int s = rp[n], e = rp[n + 1];
    const int* cs = col_sorted + (long)b * EE;
    int e4 = lane >> 4, d4 = lane & 15;
    f32x4 sum = (f32x4)(0.f);
    for (int j = s + e4; j < e; j += 4) {
        int cell = idx[cs[j]];
        sum += *(const f32x4*)&emb[(size_t)cell * DD + d4 * 4];
    }
    #pragma unroll
    for (int i = 0; i < 4; ++i) {
        sum[i] += __shfl_xor(sum[i], 16, 64);
        sum[i] += __shfl_xor(sum[i], 32, 64);
    }
    if (lane < 16) {
        s16x4 o;
        #pragma unroll
        for (int i = 0; i < 4; ++i) o[i] = (short)f2bf(sum[i]);
        *(s16x4*)&Hout[((long)b * NN + n) * DD + d4 * 4] = o;
    }
}

// Hops 2..4: bf16 rows. 8 edge slots x 8 lanes x short8 (16 B) => 8 independent
// gather chains per wave (~2 trips/lane at mean degree 16).
__global__ __launch_bounds__(256) void spmm_kernel(const short* __restrict__ Hin,
                                                   const int* __restrict__ row_ptr,
                                                   const int* __restrict__ col_sorted, short* __restrict__ Hout) {
    int wave = threadIdx.x >> 6, lane = threadIdx.x & 63;
    int b = blockIdx.x & 7;
    int n = (blockIdx.x >> 3) * 4 + wave;
    const int* rp = row_ptr + b * (NN + 1);
    int s = rp[n], e = rp[n + 1];
    const short* hb = Hin + (long)b * (NN * DD);
    const int* cs = col_sorted + (long)b * EE;
    int e8 = lane >> 3, d8 = lane & 7;
    float sum[8] = {0.f, 0.f, 0.f, 0.f, 0.f, 0.f, 0.f, 0.f};
    for (int j = s + e8; j < e; j += 8) {
        int col = cs[j];
        short8 v = *(const short8*)&hb[(size_t)col * DD + d8 * 8];
        #pragma unroll
        for (int i = 0; i < 8; ++i) sum[i] += bf2f((unsigned short)v[i]);
    }
    #pragma unroll
    for (int i = 0; i < 8; ++i) {
        sum[i] += __shfl_xor(sum[i], 8, 64);
        sum[i] += __shfl_xor(sum[i], 16, 64);
        sum[i] += __shfl_xor(sum[i], 32, 64);
    }
    if (lane < 8) {
        short8 o;
        #pragma unroll
        for (int i = 0; i < 8; ++i) o[i] = (short)f2bf(sum[i]);
        *(short8*)&Hout[((long)b * NN + n) * DD + lane * 8] = o;
    }
}

// ---------------- weight packing: bf16 B-fragment layout ----------------
// Omega is staged HOP-MAJOR: k' = h*64 + d. Compensate by permuting W1 rows here:
// fragment k' maps to original W1 row k = d*4 + h.
__global__ __launch_bounds__(256) void pack_w1_kernel(const float* __restrict__ W1, short* __restrict__ w1p) {
    int i = blockIdx.x * 256 + threadIdx.x;  // < 131072
    int j = i & 7, la = (i >> 3) & 63, kb = (i >> 9) & 7, ct = i >> 12;
    int kp = kb * 32 + ((la >> 4) & 3) * 8 + j;  // k' in [0,256), hop-major
    int h = kp >> 6, d = kp & 63;
    int k = d * 4 + h;  // reference W1 row (stack(...,-1).reshape => k = d*HOPS+h)
    int col = ct * 16 + (la & 15);
    w1p[i] = (short)f2bf(W1[k * HID + col]);
}

// W2 packed: i = ((ct*16+kb)*64+la)*8+j (unchanged ordering)
__global__ __launch_bounds__(256) void pack_w2_kernel(const float* __restrict__ W2, short* __restrict__ w2p) {
    int i = blockIdx.x * 256 + threadIdx.x;  // < 131072
    int j = i & 7, la = (i >> 3) & 63, kb = (i >> 9) & 15, ct = i >> 13;
    int k = kb * 32 + ((la >> 4) & 3) * 8 + j;
    int col = ct * 16 + (la & 15);
    w2p[i] = (short)f2bf(W2[k * OUTD + col]);
}

// ---------------- fused MFMA MLP ----------------
// 32 rows/block, 256 threads (4 waves). Wave w: GEMM1 cols [w*128,w*128+128)
// => acc[2][8] = 64 AGPR; GEMM2 cols [w*64,w*64+64) => acc2[2][4] = 32 AGPR.
// __launch_bounds__(256,4): arg2 = blocks/CU (verified empirically rounds 0-4).
// 4 blocks/CU = 16 waves/CU = 4 waves/SIMD => 128-reg budget; round 4 counters
// confirm no spills (VGPR=64, WRITE ~= output size).
// H is now bf16, so phase 1 is a pure 16 B fragment copy (no cvt).
__global__ __launch_bounds__(256, 4) void mlp_mfma_kernel(const short* __restrict__ H,  // [hop][b][n][d] bf16
                                                          const short* __restrict__ w1p,
                                                          const float* __restrict__ b1,
                                                          const float* __restrict__ gamma,
                                                          const float* __restrict__ beta,
                                                          const short* __restrict__ w2p,
                                                          const float* __restrict__ b2, float* __restrict__ out) {
    __shared__ short buf[16384];   // 32 KB: omega frags (16 KB) then xact frags (32 KB)
    __shared__ float s1a[32 * 4];  // LN partials
    __shared__ float s2a[32 * 4];
    const int t = threadIdx.x;
    const int w = t >> 6, l = t & 63;
    const int q = l >> 4, cl = l & 15;
    const int lF = swz(l);
    const long g0 = (long)blockIdx.x * 32;

    // ---- Phase 1: stage omega[32][256] (k' = h*64+d) as bf16 A-fragments ----
    // Per task: 8 consecutive bf16 d of one hop plane = 16 B contiguous global
    // = one fragment slot in LDS. 16 tasks = 4 hops x 4 row-groups.
    {
        const int rsub = l >> 3, oct = l & 7;
        #pragma unroll
        for (int i = 0; i < 4; ++i) {
            int task = i * 4 + w;
            int h = task >> 2, rg = task & 3;
            int r = rg * 8 + rsub;
            short8 frag = *(const short8*)&H[((long)h * (BG * NN) + g0 + r) * DD + oct * 8];
            int kb = (h << 1) | (oct >> 2);  // k0 = h*64+oct*8; kb = k0>>5
            int quad = oct & 3;
            int rt = r >> 4;
            int la = (r & 15) | (quad << 4);
            *(short8*)&buf[((rt * 8 + kb) * 64 + swz(la)) * 8] = frag;
        }
    }
    __syncthreads();

    // ---- Phase 2: GEMM1: acc[rt][c] = omega(32x256) @ W1(256x512) wave-slice ----
    f32x4 acc[2][8];
    #pragma unroll
    for (int rt = 0; rt < 2; ++rt)
        #pragma unroll
        for (int c = 0; c < 8; ++c) acc[rt][c] = (f32x4)(0.f);
    #pragma unroll 2
    for (int kb = 0; kb < 8; ++kb) {
        short8 a[2];
        #pragma unroll
        for (int rt = 0; rt < 2; ++rt) a[rt] = *(const short8*)&buf[((rt * 8 + kb) * 64 + lF) * 8];
        #pragma unroll
        for (int c = 0; c < 8; ++c) {
            const short8 bfr = *(const short8*)(w1p + (((size_t)(w * 8 + c) * 8 + kb) * 64 + l) * 8);
            #pragma unroll
            for (int rt = 0; rt < 2; ++rt)
                acc[rt][c] = __builtin_amdgcn_mfma_f32_16x16x32_bf16(a[rt], bfr, acc[rt][c], 0, 0, 0);
        }
    }

    // ---- Phase 3: bias + row partial sums -> LDS ----
    {
        float b1v[8];
        #pragma unroll
        for (int c = 0; c < 8; ++c) b1v[c] = b1[(w * 8 + c) * 16 + cl];
        float s1[2][4], s2[2][4];
        #pragma unroll
        for (int rt = 0; rt < 2; ++rt)
            #pragma unroll
            for (int i = 0; i < 4; ++i) {
                float a = 0.f, bb = 0.f;
                #pragma unroll
                for (int c = 0; c < 8; ++c) {
                    float x = acc[rt][c][i] + b1v[c];
                    acc[rt][c][i] = x;
                    a += x;
                    bb += x * x;
                }
                s1[rt][i] = a;
                s2[rt][i] = bb;
            }
        #pragma unroll
        for (int m = 1; m < 16; m <<= 1)
            #pragma unroll
            for (int rt = 0; rt < 2; ++rt)
                #pragma unroll
                for (int i = 0; i < 4; ++i) {
                    s1[rt][i] += __shfl_xor(s1[rt][i], m, 64);
                    s2[rt][i] += __shfl_xor(s2[rt][i], m, 64);
                }
        if (cl == 0) {
            #pragma unroll
            for (int rt = 0; rt < 2; ++rt)
                #pragma unroll
                for (int i = 0; i < 4; ++i) {
                    int row = rt * 16 + q * 4 + i;
                    s1a[row * 4 + w] = s1[rt][i];
                    s2a[row * 4 + w] = s2[rt][i];
                }
        }
    }
    __syncthreads();  // partials visible; also separates GEMM1 buf reads from phase-5 buf writes

    // ---- Phase 5: LN (stats inline from LDS partials) + GELU + repack bf16 A-frags ----
    {
        float gv[8], bv[8];
        #pragma unroll
        for (int c = 0; c < 8; ++c) {
            int col = (w * 8 + c) * 16 + cl;
            gv[c] = gamma[col];
            bv[c] = beta[col];
        }
        #pragma unroll
        for (int rt = 0; rt < 2; ++rt)
            #pragma unroll
            for (int i = 0; i < 4; ++i) {
                int row = rt * 16 + q * 4 + i;
                float a = s1a[row * 4] + s1a[row * 4 + 1] + s1a[row * 4 + 2] + s1a[row * 4 + 3];
                float bb = s2a[row * 4] + s2a[row * 4 + 1] + s2a[row * 4 + 2] + s2a[row * 4 + 3];
                float mu = a * (1.f / HID);
                float var = bb * (1.f / HID) - mu * mu;
                float rs = rsqrtf(var + 1e-5f);
                #pragma unroll
                for (int c = 0; c < 8; ++c) {
                    int col = (w * 8 + c) * 16 + cl;
                    int kb2 = col >> 5, quad2 = (col >> 3) & 3, j2 = col & 7;
                    float x = (acc[rt][c][i] - mu) * rs * gv[c] + bv[c];
                    float g = 0.5f * x * (1.f + erff(x * 0.70710678118654752f));
                    int la = swz((q * 4 + i) | (quad2 << 4));
                    buf[((rt * 16 + kb2) * 64 + la) * 8 + j2] = (short)f2bf(g);
                }
            }
    }
    __syncthreads();

    // ---- Phase 6: GEMM2: out-slice = xact(32x512) @ W2(512x256) ----
    f32x4 acc2[2][4];
    #pragma unroll
    for (int rt = 0; rt < 2; ++rt)
        #pragma unroll
        for (int c = 0; c < 4; ++c) acc2[rt][c] = (f32x4)(0.f);
    #pragma unroll 2
    for (int kb = 0; kb < 16; ++kb) {
        short8 a[2];
        #pragma unroll
        for (int rt = 0; rt < 2; ++rt) a[rt] = *(const short8*)&buf[((rt * 16 + kb) * 64 + lF) * 8];
        #pragma unroll
        for (int c = 0; c < 4; ++c) {
            const short8 bfr = *(const short8*)(w2p + (((size_t)(w * 4 + c) * 16 + kb) * 64 + l) * 8);
            #pragma unroll
            for (int rt = 0; rt < 2; ++rt)
                acc2[rt][c] = __builtin_amdgcn_mfma_f32_16x16x32_bf16(a[rt], bfr, acc2[rt][c], 0, 0, 0);
        }
    }

    // ---- Phase 7: bias + store ----
    float b2v[4];
    #pragma unroll
    for (int c = 0; c < 4; ++c) b2v[c] = b2[(w * 4 + c) * 16 + cl];
    #pragma unroll
    for (int rt = 0; rt < 2; ++rt)
        #pragma unroll
        for (int c = 0; c < 4; ++c)
            #pragma unroll
            for (int i = 0; i < 4; ++i) {
                long g = g0 + rt * 16 + q * 4 + i;
                out[g * OUTD + (w * 4 + c) * 16 + cl] = acc2[rt][c][i] + b2v[c];
            }
}

// ---------------- launch ----------------

extern "C" void kernel_launch(void* const* d_in, const int* in_sizes, int n_in, void* d_out, int out_size,
                              void* d_ws, size_t ws_size, hipStream_t stream) {
    const int* ei = (const int*)d_in[0];
    const float* P = (const float*)d_in[2];
    const float* emb = (const float*)d_in[3];
    const float* W1 = (const float*)d_in[4];
    const float* b1 = (const float*)d_in[5];
    const float* gamma = (const float*)d_in[6];
    const float* beta = (const float*)d_in[7];
    const float* W2 = (const float*)d_in[8];
    const float* b2 = (const float*)d_in[9];
    float* out = (float*)d_out;

    char* ws = (char*)d_ws;
    size_t off = 0;
    auto alloc = [&](size_t bytes) -> char* {
        char* p = ws + off;
        off += (bytes + 1023) & ~(size_t)1023;
        return p;
    };
    int* idx = (int*)alloc((size_t)NN * 4);
    int* counts = (int*)alloc((size_t)BG * NN * 4);
    int* row_ptr = (int*)alloc((size_t)BG * (NN + 1) * 4);
    int* cursor = (int*)alloc((size_t)BG * NN * 4);
    int* col_sorted = (int*)alloc((size_t)BG * EE * 4);
    short* w1p = (short*)alloc((size_t)131072 * 2);
    short* w2p = (short*)alloc((size_t)131072 * 2);
    short* H = (short*)alloc((size_t)NHOPS * BG * NN * DD * 2);  // bf16 hops

    hipLaunchKernelGGL(zero_kernel, dim3((BG * NN + 255) / 256), dim3(256), 0, stream, counts, BG * NN);
    hipLaunchKernelGGL(argmax_kernel, dim3((NN + 255) / 256), dim3(256), 0, stream, P, idx);
    hipLaunchKernelGGL(hist_kernel, dim3(BG * EE / 256), dim3(256), 0, stream, ei, counts);
    hipLaunchKernelGGL(scan_kernel, dim3(BG), dim3(256), 0, stream, counts, row_ptr, cursor);
    hipLaunchKernelGGL(scatter_kernel, dim3(BG * EE / 256), dim3(256), 0, stream, ei, cursor, col_sorted);
    hipLaunchKernelGGL(pack_w1_kernel, dim3(512), dim3(256), 0, stream, W1, w1p);
    hipLaunchKernelGGL(pack_w2_kernel, dim3(512), dim3(256), 0, stream, W2, w2p);

    const long hs = (long)BG * NN * DD;
    hipLaunchKernelGGL(spmm_first_kernel, dim3(BG * NN / 4), dim3(256), 0, stream, idx, emb, row_ptr, col_sorted, H);
    for (int h = 1; h < NHOPS; ++h) {
        hipLaunchKernelGGL(spmm_kernel, dim3(BG * NN / 4), dim3(256), 0, stream, H + (long)(h - 1) * hs, row_ptr,
                           col_sorted, H + (long)h * hs);
    }
    hipLaunchKernelGGL(mlp_mfma_kernel, dim3(BG * NN / 32), dim3(256), 0, stream, H, w1p, b1, gamma, beta, w2p, b2,
                       out);
}